// Round 12
// baseline (248.952 us; speedup 1.0000x reference)
//
#include <hip/hip_runtime.h>
#include <hip/hip_bf16.h>

#define NN 100000   // nodes
#define NE 600000   // edges (self-loop handled analytically)
#define NBLK 391    // ceil(NN/256)
#define NPAD 100096 // row padding for GEMM tiles (row NN = zero row)

typedef unsigned int uint;
typedef unsigned short ushort;
typedef __attribute__((ext_vector_type(8))) short bf16x8;
typedef __attribute__((ext_vector_type(4))) float f32x4;

__device__ __forceinline__ ushort f2b(float f) {
    union { float f; uint u; } v; v.f = f;
    return (ushort)((v.u + 0x7fffu + ((v.u >> 16) & 1u)) >> 16);
}
__device__ __forceinline__ uint f2b2(float lo, float hi) {
    return (uint)f2b(lo) | ((uint)f2b(hi) << 16);
}
__device__ __forceinline__ float b2f(uint h) {
    union { uint u; float f; } v; v.u = h << 16; return v.f;
}

// ================= CSR build =================
__global__ __launch_bounds__(256) void k_init_castW(int* __restrict__ cnt,
                                                    const float* __restrict__ W1,
                                                    const float* __restrict__ W2,
                                                    const float* __restrict__ W3,
                                                    ushort* __restrict__ WTall) {
    int t = threadIdx.x;
    if (blockIdx.x < NBLK) {
        int i = blockIdx.x * 256 + t;
        if (i < NN) cnt[i] = 0;
    } else {
        int o = (blockIdx.x - NBLK) * 256 + t;
        if (o >= 38912) return;
        float v;
        if (o < 32768) {
            const float* W = (o < 16384) ? W1 : W2;
            int off = o & 16383;
            int n = off >> 7, k = off & 127;
            v = W[k * 128 + n];
        } else {
            int off = o - 32768;
            int n = off >> 7, k = off & 127;
            v = (n < 40) ? W3[k * 40 + n] : 0.f;
        }
        WTall[o] = f2b(v);
    }
}
__global__ __launch_bounds__(256) void k_cnt(const int* __restrict__ dst,
                                             int* __restrict__ cnt,
                                             int* __restrict__ rank) {
    int e = blockIdx.x * 256 + threadIdx.x;
    if (e < NE) rank[e] = atomicAdd(&cnt[dst[e]], 1);
}
__global__ __launch_bounds__(256) void k_blockred(const int* __restrict__ cnt,
                                                  int* __restrict__ blocksum) {
    int t = threadIdx.x;
    int i = blockIdx.x * 256 + t;
    int c = (i < NN) ? cnt[i] : 0;
    #pragma unroll
    for (int o = 32; o; o >>= 1) c += __shfl_xor(c, o, 64);
    __shared__ int ws[4];
    if ((t & 63) == 0) ws[t >> 6] = c;
    __syncthreads();
    if (t == 0) blocksum[blockIdx.x] = ws[0] + ws[1] + ws[2] + ws[3];
}
// offsets + dis; block prefix self-computed from blocksum (scanblk merged in)
__global__ __launch_bounds__(256) void k_offsets(const int* __restrict__ cnt,
                                                 const int* __restrict__ blocksum,
                                                 int* __restrict__ offsets,
                                                 float* __restrict__ dis) {
    int t = threadIdx.x, lane = t & 63, wv = t >> 6;
    const int bid = blockIdx.x;
    // base = sum of blocksum[0..bid)
    __shared__ int red[4];
    int part = 0;
    for (int i = t; i < bid; i += 256) part += blocksum[i];
    #pragma unroll
    for (int o = 32; o; o >>= 1) part += __shfl_xor(part, o, 64);
    if (lane == 0) red[wv] = part;
    __syncthreads();
    int base = red[0] + red[1] + red[2] + red[3];

    int i = bid * 256 + t;
    int c = (i < NN) ? cnt[i] : 0;
    int x = c;
    #pragma unroll
    for (int o = 1; o < 64; o <<= 1) {
        int v = __shfl_up(x, o, 64);
        if (lane >= o) x += v;
    }
    __shared__ int wsum[4], wbase[4];
    if (lane == 63) wsum[wv] = x;
    __syncthreads();
    if (t == 0) {
        int run = 0;
        #pragma unroll
        for (int k = 0; k < 4; ++k) { wbase[k] = run; run += wsum[k]; }
    }
    __syncthreads();
    int excl = base + wbase[wv] + x - c;
    if (i < NN) {
        offsets[i] = excl;
        dis[i] = rsqrtf((float)(c + 1));
        if (i == NN - 1) offsets[NN] = excl + c;
    }
}
__global__ __launch_bounds__(256) void k_fill(const int* __restrict__ src,
                                              const int* __restrict__ dst,
                                              const int* __restrict__ rank,
                                              const int* __restrict__ offsets,
                                              int* __restrict__ edges) {
    int e = blockIdx.x * 256 + threadIdx.x;
    if (e < NE) {
        int s = src[e], d = dst[e], r = rank[e];
        edges[offsets[d] + r] = s;
    }
}

// ================= GEMM layer 1: G1[N,128] = dis[row]*(feat @ W1), fp32 in =========
// Two-pass B (17.4 KB halves) -> 34.8 KB LDS -> 4 blocks/CU.
__global__ __launch_bounds__(256, 4) void k_gemm1(const float* __restrict__ Xf,
                                                  const ushort* __restrict__ WT,
                                                  const float* __restrict__ dis,
                                                  ushort* __restrict__ Yb) {
    __shared__ ushort AL[64 * 136];
    __shared__ ushort BL[64 * 136];
    const int t = threadIdx.x;
    const int rbase = blockIdx.x * 64;
    if (blockIdx.x == 0 && t < 16) {   // zero row NN (gather target for pad lanes)
        uint4 z = make_uint4(0, 0, 0, 0);
        ((uint4*)(Yb + (size_t)NN * 128))[t] = z;
    }
    #pragma unroll
    for (int i = 0; i < 4; ++i) {
        int ch = t + 256 * i;
        int n = ch >> 4, c = ch & 15;
        *(int4*)(BL + n * 136 + c * 8) = *(const int4*)(WT + n * 128 + c * 8);
    }
    #pragma unroll
    for (int i = 0; i < 4; ++i) {
        int ch = t + 256 * i;
        int m = ch >> 4, c = ch & 15;
        int row = min(rbase + m, NN - 1);
        float4 f0 = *(const float4*)(Xf + (size_t)row * 128 + c * 8);
        float4 f1 = *(const float4*)(Xf + (size_t)row * 128 + c * 8 + 4);
        uint4 o;
        o.x = f2b2(f0.x, f0.y);
        o.y = f2b2(f0.z, f0.w);
        o.z = f2b2(f1.x, f1.y);
        o.w = f2b2(f1.z, f1.w);
        *(uint4*)(AL + m * 136 + c * 8) = o;
    }
    __syncthreads();
    const int wv = t >> 6, l = t & 63;
    const int m16 = l & 15, q = l >> 4;
    f32x4 acc[8];
    #pragma unroll
    for (int j = 0; j < 8; ++j) acc[j] = (f32x4){0.f, 0.f, 0.f, 0.f};
    #pragma unroll
    for (int kt = 0; kt < 4; ++kt) {
        bf16x8 a = *(const bf16x8*)(AL + (wv * 16 + m16) * 136 + kt * 32 + q * 8);
        #pragma unroll
        for (int j = 0; j < 4; ++j) {
            bf16x8 b = *(const bf16x8*)(BL + (j * 16 + m16) * 136 + kt * 32 + q * 8);
            acc[j] = __builtin_amdgcn_mfma_f32_16x16x32_bf16(a, b, acc[j], 0, 0, 0);
        }
    }
    __syncthreads();
    #pragma unroll
    for (int i = 0; i < 4; ++i) {
        int ch = t + 256 * i;
        int n = ch >> 4, c = ch & 15;
        *(int4*)(BL + n * 136 + c * 8) = *(const int4*)(WT + (64 + n) * 128 + c * 8);
    }
    __syncthreads();
    #pragma unroll
    for (int kt = 0; kt < 4; ++kt) {
        bf16x8 a = *(const bf16x8*)(AL + (wv * 16 + m16) * 136 + kt * 32 + q * 8);
        #pragma unroll
        for (int j = 0; j < 4; ++j) {
            bf16x8 b = *(const bf16x8*)(BL + (j * 16 + m16) * 136 + kt * 32 + q * 8);
            acc[4 + j] = __builtin_amdgcn_mfma_f32_16x16x32_bf16(a, b, acc[4 + j], 0, 0, 0);
        }
    }
    #pragma unroll
    for (int r = 0; r < 4; ++r) {
        int row = rbase + wv * 16 + q * 4 + r;
        if (row < NN) {
            float ds = dis[row];
            #pragma unroll
            for (int j = 0; j < 8; ++j)
                Yb[(size_t)row * 128 + j * 16 + m16] = f2b(acc[j][r] * ds);
        }
    }
}

// ======= FUSED: aggregate(G_prev) + bias + relu -> LDS -> GEMM(W,128) -> G_next =======
// FOUR-pass B (32 n-rows, 8.7 KB) -> LDS 26.1 KB -> 6 blocks/CU for the agg phase.
__global__ __launch_bounds__(256, 6) void k_fused128(const int* __restrict__ offsets,
                                                     const int* __restrict__ edges,
                                                     const float* __restrict__ dis,
                                                     const ushort* __restrict__ xw,
                                                     const float* __restrict__ bias,
                                                     const ushort* __restrict__ WT,
                                                     ushort* __restrict__ out) {
    __shared__ ushort AL[64 * 136];
    __shared__ ushort BL[32 * 136];
    const int t = threadIdx.x;
    const int rbase = blockIdx.x * 64;
    if (blockIdx.x == 0 && t < 16) {   // zero row NN of the OUTPUT buffer
        uint4 z = make_uint4(0, 0, 0, 0);
        ((uint4*)(out + (size_t)NN * 128))[t] = z;
    }
    // stage B pass 0 (n-rows 0..31); overlaps agg latency
    #pragma unroll
    for (int i = 0; i < 2; ++i) {
        int ch = t + 256 * i;
        int n = ch >> 4, c = ch & 15;
        *(int4*)(BL + n * 136 + c * 8) = *(const int4*)(WT + n * 128 + c * 8);
    }
    const int wv = t >> 6, lane = t & 63;
    const int hl = lane & 15;
    const int qsel = lane & 48;
    const int qid = wv * 4 + (lane >> 4);   // 0..15
    #pragma unroll
    for (int iter = 0; iter < 4; ++iter) {
        const int m = qid * 4 + iter;
        const int n = rbase + m;
        const int nc = min(n, NN - 1);
        const int beg = offsets[nc], end = offsets[nc + 1];
        const int deg = end - beg;
        int s_l = (hl < deg) ? edges[beg + hl] : NN;   // NN = zero row
        uint4 v0 = ((const uint4*)(xw + (size_t)nc * 128))[hl];
        float a0 = b2f(v0.x & 0xffffu), a1 = b2f(v0.x >> 16);
        float a2 = b2f(v0.y & 0xffffu), a3 = b2f(v0.y >> 16);
        float a4 = b2f(v0.z & 0xffffu), a5 = b2f(v0.z >> 16);
        float a6 = b2f(v0.w & 0xffffu), a7 = b2f(v0.w >> 16);
        int degc = min(deg, 16);
        int qceil = (degc + 7) & ~7;                  // own quarter's ceiling
        int m1 = max(degc, __shfl_xor(degc, 16, 64));
        int dmax = max(m1, __shfl_xor(m1, 32, 64));
        int jceil = (dmax + 7) & ~7;
        for (int j = 0; j < jceil; j += 8) {
            if (j < qceil) {                          // quarter-uniform guard
                int s[8]; uint4 u[8];
                #pragma unroll
                for (int k = 0; k < 8; ++k) s[k] = __shfl(s_l, qsel + j + k, 64);
                #pragma unroll
                for (int k = 0; k < 8; ++k)
                    u[k] = ((const uint4*)(xw + (size_t)s[k] * 128))[hl];
                #pragma unroll
                for (int k = 0; k < 8; ++k) {
                    a0 += b2f(u[k].x & 0xffffu); a1 += b2f(u[k].x >> 16);
                    a2 += b2f(u[k].y & 0xffffu); a3 += b2f(u[k].y >> 16);
                    a4 += b2f(u[k].z & 0xffffu); a5 += b2f(u[k].z >> 16);
                    a6 += b2f(u[k].w & 0xffffu); a7 += b2f(u[k].w >> 16);
                }
            }
        }
        for (int jj = beg + 16; jj < end; ++jj) {   // deg>16 tail (rare)
            int s2 = edges[jj];
            uint4 u = ((const uint4*)(xw + (size_t)s2 * 128))[hl];
            a0 += b2f(u.x & 0xffffu); a1 += b2f(u.x >> 16);
            a2 += b2f(u.y & 0xffffu); a3 += b2f(u.y >> 16);
            a4 += b2f(u.z & 0xffffu); a5 += b2f(u.z >> 16);
            a6 += b2f(u.w & 0xffffu); a7 += b2f(u.w >> 16);
        }
        float d = dis[nc];
        float4 bv0 = ((const float4*)bias)[2 * hl];
        float4 bv1 = ((const float4*)bias)[2 * hl + 1];
        a0 = fmaxf(fmaf(a0, d, bv0.x), 0.f); a1 = fmaxf(fmaf(a1, d, bv0.y), 0.f);
        a2 = fmaxf(fmaf(a2, d, bv0.z), 0.f); a3 = fmaxf(fmaf(a3, d, bv0.w), 0.f);
        a4 = fmaxf(fmaf(a4, d, bv1.x), 0.f); a5 = fmaxf(fmaf(a5, d, bv1.y), 0.f);
        a6 = fmaxf(fmaf(a6, d, bv1.z), 0.f); a7 = fmaxf(fmaf(a7, d, bv1.w), 0.f);
        uint4 o;
        o.x = f2b2(a0, a1);
        o.y = f2b2(a2, a3);
        o.z = f2b2(a4, a5);
        o.w = f2b2(a6, a7);
        *(uint4*)(AL + m * 136 + hl * 8) = o;
    }
    __syncthreads();
    const int m16 = lane & 15, q = lane >> 4;
    f32x4 acc[8];
    #pragma unroll
    for (int j = 0; j < 8; ++j) acc[j] = (f32x4){0.f, 0.f, 0.f, 0.f};
    // 4 passes: pass p computes n-tiles {2p, 2p+1} from BL (32 cols each pass)
    #pragma unroll
    for (int p = 0; p < 4; ++p) {
        if (p > 0) {
            __syncthreads();   // previous pass's BL reads done
            #pragma unroll
            for (int i = 0; i < 2; ++i) {
                int ch = t + 256 * i;
                int n = ch >> 4, c = ch & 15;
                *(int4*)(BL + n * 136 + c * 8) =
                    *(const int4*)(WT + (p * 32 + n) * 128 + c * 8);
            }
            __syncthreads();
        }
        #pragma unroll
        for (int kt = 0; kt < 4; ++kt) {
            bf16x8 a = *(const bf16x8*)(AL + (wv * 16 + m16) * 136 + kt * 32 + q * 8);
            #pragma unroll
            for (int jj = 0; jj < 2; ++jj) {
                bf16x8 b = *(const bf16x8*)(BL + (jj * 16 + m16) * 136 + kt * 32 + q * 8);
                acc[p * 2 + jj] =
                    __builtin_amdgcn_mfma_f32_16x16x32_bf16(a, b, acc[p * 2 + jj], 0, 0, 0);
            }
        }
    }
    #pragma unroll
    for (int r = 0; r < 4; ++r) {
        int row = rbase + wv * 16 + q * 4 + r;
        if (row < NN) {
            float ds = dis[row];
            #pragma unroll
            for (int j = 0; j < 8; ++j)
                out[(size_t)row * 128 + j * 16 + m16] = f2b(acc[j][r] * ds);
        }
    }
}

// ======= FUSED: aggregate(G2) + bias + relu -> LDS -> GEMM(W3,48) -> Y40b =======
__global__ __launch_bounds__(256, 5) void k_fused40(const int* __restrict__ offsets,
                                                    const int* __restrict__ edges,
                                                    const float* __restrict__ dis,
                                                    const ushort* __restrict__ xw,
                                                    const float* __restrict__ bias,
                                                    const ushort* __restrict__ W3T,
                                                    ushort* __restrict__ out) {
    __shared__ ushort AL[64 * 136];
    __shared__ ushort BL[48 * 136];
    const int t = threadIdx.x;
    const int rbase = blockIdx.x * 64;
    if (blockIdx.x == 0 && t < 8) {   // zero row NN of Y40b (stride 64)
        uint4 z = make_uint4(0, 0, 0, 0);
        ((uint4*)(out + (size_t)NN * 64))[t] = z;
    }
    #pragma unroll
    for (int i = 0; i < 3; ++i) {
        int ch = t + 256 * i;
        int n = ch >> 4, c = ch & 15;
        *(int4*)(BL + n * 136 + c * 8) = *(const int4*)(W3T + n * 128 + c * 8);
    }
    const int wv = t >> 6, lane = t & 63;
    const int hl = lane & 15;
    const int qsel = lane & 48;
    const int qid = wv * 4 + (lane >> 4);
    #pragma unroll
    for (int iter = 0; iter < 4; ++iter) {
        const int m = qid * 4 + iter;
        const int n = rbase + m;
        const int nc = min(n, NN - 1);
        const int beg = offsets[nc], end = offsets[nc + 1];
        const int deg = end - beg;
        int s_l = (hl < deg) ? edges[beg + hl] : NN;
        uint4 v0 = ((const uint4*)(xw + (size_t)nc * 128))[hl];
        float a0 = b2f(v0.x & 0xffffu), a1 = b2f(v0.x >> 16);
        float a2 = b2f(v0.y & 0xffffu), a3 = b2f(v0.y >> 16);
        float a4 = b2f(v0.z & 0xffffu), a5 = b2f(v0.z >> 16);
        float a6 = b2f(v0.w & 0xffffu), a7 = b2f(v0.w >> 16);
        int degc = min(deg, 16);
        int qceil = (degc + 7) & ~7;
        int m1 = max(degc, __shfl_xor(degc, 16, 64));
        int dmax = max(m1, __shfl_xor(m1, 32, 64));
        int jceil = (dmax + 7) & ~7;
        for (int j = 0; j < jceil; j += 8) {
            if (j < qceil) {
                int s[8]; uint4 u[8];
                #pragma unroll
                for (int k = 0; k < 8; ++k) s[k] = __shfl(s_l, qsel + j + k, 64);
                #pragma unroll
                for (int k = 0; k < 8; ++k)
                    u[k] = ((const uint4*)(xw + (size_t)s[k] * 128))[hl];
                #pragma unroll
                for (int k = 0; k < 8; ++k) {
                    a0 += b2f(u[k].x & 0xffffu); a1 += b2f(u[k].x >> 16);
                    a2 += b2f(u[k].y & 0xffffu); a3 += b2f(u[k].y >> 16);
                    a4 += b2f(u[k].z & 0xffffu); a5 += b2f(u[k].z >> 16);
                    a6 += b2f(u[k].w & 0xffffu); a7 += b2f(u[k].w >> 16);
                }
            }
        }
        for (int jj = beg + 16; jj < end; ++jj) {
            int s2 = edges[jj];
            uint4 u = ((const uint4*)(xw + (size_t)s2 * 128))[hl];
            a0 += b2f(u.x & 0xffffu); a1 += b2f(u.x >> 16);
            a2 += b2f(u.y & 0xffffu); a3 += b2f(u.y >> 16);
            a4 += b2f(u.z & 0xffffu); a5 += b2f(u.z >> 16);
            a6 += b2f(u.w & 0xffffu); a7 += b2f(u.w >> 16);
        }
        float d = dis[nc];
        float4 bv0 = ((const float4*)bias)[2 * hl];
        float4 bv1 = ((const float4*)bias)[2 * hl + 1];
        a0 = fmaxf(fmaf(a0, d, bv0.x), 0.f); a1 = fmaxf(fmaf(a1, d, bv0.y), 0.f);
        a2 = fmaxf(fmaf(a2, d, bv0.z), 0.f); a3 = fmaxf(fmaf(a3, d, bv0.w), 0.f);
        a4 = fmaxf(fmaf(a4, d, bv1.x), 0.f); a5 = fmaxf(fmaf(a5, d, bv1.y), 0.f);
        a6 = fmaxf(fmaf(a6, d, bv1.z), 0.f); a7 = fmaxf(fmaf(a7, d, bv1.w), 0.f);
        uint4 o;
        o.x = f2b2(a0, a1);
        o.y = f2b2(a2, a3);
        o.z = f2b2(a4, a5);
        o.w = f2b2(a6, a7);
        *(uint4*)(AL + m * 136 + hl * 8) = o;
    }
    __syncthreads();
    const int m16 = lane & 15, q = lane >> 4;
    f32x4 acc[3];
    #pragma unroll
    for (int j = 0; j < 3; ++j) acc[j] = (f32x4){0.f, 0.f, 0.f, 0.f};
    #pragma unroll
    for (int kt = 0; kt < 4; ++kt) {
        bf16x8 a = *(const bf16x8*)(AL + (wv * 16 + m16) * 136 + kt * 32 + q * 8);
        #pragma unroll
        for (int j = 0; j < 3; ++j) {
            bf16x8 b = *(const bf16x8*)(BL + (j * 16 + m16) * 136 + kt * 32 + q * 8);
            acc[j] = __builtin_amdgcn_mfma_f32_16x16x32_bf16(a, b, acc[j], 0, 0, 0);
        }
    }
    #pragma unroll
    for (int r = 0; r < 4; ++r) {
        int row = rbase + wv * 16 + q * 4 + r;
        if (row < NN) {
            float ds = dis[row];
            #pragma unroll
            for (int j = 0; j < 3; ++j)
                out[(size_t)row * 64 + j * 16 + m16] = f2b(acc[j][r] * ds);
        }
    }
}

// ===== fused aggregate + bias + relu + log_softmax, F=40: FOUR nodes/wave =====
__global__ __launch_bounds__(256) void k_agg40_lsm(const int* __restrict__ offsets,
                                                   const int* __restrict__ edges,
                                                   const float* __restrict__ dis,
                                                   const ushort* __restrict__ xw,
                                                   const float* __restrict__ bias,
                                                   float* __restrict__ out) {
    const int t = threadIdx.x;
    const int wv = t >> 6, lane = t & 63;
    const int hl = lane & 15;
    const int qsel = lane & 48;
    const int n = (blockIdx.x * 4 + wv) * 4 + (lane >> 4);
    const bool nvalid = n < NN;
    const int nc = nvalid ? n : NN - 1;
    const bool act = hl < 10;   // lanes 0..9 hold feats 4*hl..4*hl+3 (40 total)
    const int beg = offsets[nc], end = offsets[nc + 1];
    const int deg = end - beg;
    int s_l = (hl < deg) ? edges[beg + hl] : NN;
    uint2 v0 = ((const uint2*)(xw + (size_t)nc * 64))[hl];
    float x0 = b2f(v0.x & 0xffffu), x1 = b2f(v0.x >> 16);
    float x2 = b2f(v0.y & 0xffffu), x3 = b2f(v0.y >> 16);
    int degc = min(deg, 16);
    int qceil = (degc + 7) & ~7;
    int m1 = max(degc, __shfl_xor(degc, 16, 64));
    int dmax = max(m1, __shfl_xor(m1, 32, 64));
    int jceil = (dmax + 7) & ~7;
    for (int j = 0; j < jceil; j += 8) {
        if (j < qceil) {
            int s[8]; uint2 u[8];
            #pragma unroll
            for (int k = 0; k < 8; ++k) s[k] = __shfl(s_l, qsel + j + k, 64);
            #pragma unroll
            for (int k = 0; k < 8; ++k)
                u[k] = ((const uint2*)(xw + (size_t)s[k] * 64))[hl];
            #pragma unroll
            for (int k = 0; k < 8; ++k) {
                x0 += b2f(u[k].x & 0xffffu); x1 += b2f(u[k].x >> 16);
                x2 += b2f(u[k].y & 0xffffu); x3 += b2f(u[k].y >> 16);
            }
        }
    }
    for (int jj = beg + 16; jj < end; ++jj) {
        int s2 = edges[jj];
        uint2 u = ((const uint2*)(xw + (size_t)s2 * 64))[hl];
        x0 += b2f(u.x & 0xffffu); x1 += b2f(u.x >> 16);
        x2 += b2f(u.y & 0xffffu); x3 += b2f(u.y >> 16);
    }
    float d = dis[nc];
    if (act) {
        float4 bv = ((const float4*)bias)[hl];
        x0 = fmaxf(fmaf(x0, d, bv.x), 0.f);
        x1 = fmaxf(fmaf(x1, d, bv.y), 0.f);
        x2 = fmaxf(fmaf(x2, d, bv.z), 0.f);
        x3 = fmaxf(fmaf(x3, d, bv.w), 0.f);
    }
    float m = act ? fmaxf(fmaxf(x0, x1), fmaxf(x2, x3)) : -1e30f;
    #pragma unroll
    for (int o = 8; o; o >>= 1) m = fmaxf(m, __shfl_xor(m, o, 64));
    float e = act ? (expf(x0 - m) + expf(x1 - m) + expf(x2 - m) + expf(x3 - m)) : 0.f;
    #pragma unroll
    for (int o = 8; o; o >>= 1) e += __shfl_xor(e, o, 64);
    if (act && nvalid) {
        float lg = m + logf(e);
        float4 o4 = make_float4(x0 - lg, x1 - lg, x2 - lg, x3 - lg);
        *(float4*)(out + (size_t)n * 40 + 4 * hl) = o4;
    }
}

// ================= launch =================
extern "C" void kernel_launch(void* const* d_in, const int* in_sizes, int n_in,
                              void* d_out, int out_size, void* d_ws, size_t ws_size,
                              hipStream_t stream) {
    const float* feat = (const float*)d_in[0];
    const int* ei = (const int*)d_in[1];
    const float* W1 = (const float*)d_in[2];
    const float* b1 = (const float*)d_in[3];
    const float* W2 = (const float*)d_in[4];
    const float* b2 = (const float*)d_in[5];
    const float* W3 = (const float*)d_in[6];
    const float* b3 = (const float*)d_in[7];
    const int* src = ei;
    const int* dst = ei + NE;
    float* out = (float*)d_out;

    char* w = (char*)d_ws;
    int* cnt = (int*)w;        w += 100352 * 4;
    float* dis = (float*)w;    w += 100352 * 4;
    int* offsets = (int*)w;    w += 100608 * 4;
    int* rank = (int*)w;       w += 600064 * 4;
    int* blocksum = (int*)w;   w += 512 * 4;
    int* edges = (int*)w;      w += 600064 * 4;
    ushort* WTall = (ushort*)w; w += 39168 * 2;
    ushort* W1T = WTall;
    ushort* W2T = WTall + 16384;
    ushort* W3T = WTall + 32768;
    ushort* bufYb = (ushort*)w; w += (size_t)NPAD * 128 * 2;
    ushort* bufXb = (ushort*)w; w += (size_t)NPAD * 128 * 2;
    ushort* Y40b = (ushort*)w;  w += (size_t)NPAD * 64 * 2;

    const int B = 256;
    #define CDIV(a, b) (((a) + (b) - 1) / (b))

    // CSR build (reused by all layers); weight cast rides the first launch
    k_init_castW<<<NBLK + CDIV(38912, B), B, 0, stream>>>(cnt, W1, W2, W3, WTall);
    k_cnt<<<CDIV(NE, B), B, 0, stream>>>(dst, cnt, rank);
    k_blockred<<<NBLK, B, 0, stream>>>(cnt, blocksum);
    k_offsets<<<NBLK, B, 0, stream>>>(cnt, blocksum, offsets, dis);
    k_fill<<<CDIV(NE, B), B, 0, stream>>>(src, dst, rank, offsets, edges);

    // layer 1 GEMM (fp32 input, fused cast; epilogue scales by dis)
    k_gemm1<<<CDIV(NN, 64), B, 0, stream>>>(feat, W1T, dis, bufYb);
    // fused agg1 + gemm2 (four-pass B, 6 blocks/CU)
    k_fused128<<<CDIV(NN, 64), B, 0, stream>>>(offsets, edges, dis, bufYb, b1, W2T, bufXb);
    // fused agg2 + gemm40
    k_fused40<<<CDIV(NN, 64), B, 0, stream>>>(offsets, edges, dis, bufXb, b2, W3T, Y40b);
    // final aggregate + log_softmax (4 nodes/wave)
    k_agg40_lsm<<<CDIV(NN, 16), B, 0, stream>>>(offsets, edges, dis, Y40b, b3, out);
    #undef CDIV
}

// Round 13
// 235.187 us; speedup vs baseline: 1.0585x; 1.0585x over previous
//
#include <hip/hip_runtime.h>
#include <hip/hip_bf16.h>

#define NN 100000   // nodes
#define NE 600000   // edges (self-loop handled analytically)
#define NBLK 391    // ceil(NN/256)
#define NPAD 100096 // row padding for GEMM tiles (row NN = zero row)

typedef unsigned int uint;
typedef unsigned short ushort;
typedef __attribute__((ext_vector_type(8))) short bf16x8;
typedef __attribute__((ext_vector_type(4))) float f32x4;

__device__ __forceinline__ ushort f2b(float f) {
    union { float f; uint u; } v; v.f = f;
    return (ushort)((v.u + 0x7fffu + ((v.u >> 16) & 1u)) >> 16);
}
__device__ __forceinline__ uint f2b2(float lo, float hi) {
    return (uint)f2b(lo) | ((uint)f2b(hi) << 16);
}
__device__ __forceinline__ float b2f(uint h) {
    union { uint u; float f; } v; v.u = h << 16; return v.f;
}

// ================= CSR build =================
__global__ __launch_bounds__(256) void k_init_castW(int* __restrict__ cnt,
                                                    const float* __restrict__ W1,
                                                    const float* __restrict__ W2,
                                                    const float* __restrict__ W3,
                                                    ushort* __restrict__ WTall) {
    int t = threadIdx.x;
    if (blockIdx.x < NBLK) {
        int i = blockIdx.x * 256 + t;
        if (i < NN) cnt[i] = 0;
    } else {
        int o = (blockIdx.x - NBLK) * 256 + t;
        if (o >= 38912) return;
        float v;
        if (o < 32768) {
            const float* W = (o < 16384) ? W1 : W2;
            int off = o & 16383;
            int n = off >> 7, k = off & 127;
            v = W[k * 128 + n];
        } else {
            int off = o - 32768;
            int n = off >> 7, k = off & 127;
            v = (n < 40) ? W3[k * 40 + n] : 0.f;
        }
        WTall[o] = f2b(v);
    }
}
__global__ __launch_bounds__(256) void k_cnt(const int* __restrict__ dst,
                                             int* __restrict__ cnt,
                                             int* __restrict__ rank) {
    int e = blockIdx.x * 256 + threadIdx.x;
    if (e < NE) rank[e] = atomicAdd(&cnt[dst[e]], 1);
}
__global__ __launch_bounds__(256) void k_blockred(const int* __restrict__ cnt,
                                                  int* __restrict__ blocksum) {
    int t = threadIdx.x;
    int i = blockIdx.x * 256 + t;
    int c = (i < NN) ? cnt[i] : 0;
    #pragma unroll
    for (int o = 32; o; o >>= 1) c += __shfl_xor(c, o, 64);
    __shared__ int ws[4];
    if ((t & 63) == 0) ws[t >> 6] = c;
    __syncthreads();
    if (t == 0) blocksum[blockIdx.x] = ws[0] + ws[1] + ws[2] + ws[3];
}
// offsets + dis; block prefix self-computed from blocksum (scanblk merged in)
__global__ __launch_bounds__(256) void k_offsets(const int* __restrict__ cnt,
                                                 const int* __restrict__ blocksum,
                                                 int* __restrict__ offsets,
                                                 float* __restrict__ dis) {
    int t = threadIdx.x, lane = t & 63, wv = t >> 6;
    const int bid = blockIdx.x;
    __shared__ int red[4];
    int part = 0;
    for (int i = t; i < bid; i += 256) part += blocksum[i];
    #pragma unroll
    for (int o = 32; o; o >>= 1) part += __shfl_xor(part, o, 64);
    if (lane == 0) red[wv] = part;
    __syncthreads();
    int base = red[0] + red[1] + red[2] + red[3];

    int i = bid * 256 + t;
    int c = (i < NN) ? cnt[i] : 0;
    int x = c;
    #pragma unroll
    for (int o = 1; o < 64; o <<= 1) {
        int v = __shfl_up(x, o, 64);
        if (lane >= o) x += v;
    }
    __shared__ int wsum[4], wbase[4];
    if (lane == 63) wsum[wv] = x;
    __syncthreads();
    if (t == 0) {
        int run = 0;
        #pragma unroll
        for (int k = 0; k < 4; ++k) { wbase[k] = run; run += wsum[k]; }
    }
    __syncthreads();
    int excl = base + wbase[wv] + x - c;
    if (i < NN) {
        offsets[i] = excl;
        dis[i] = rsqrtf((float)(c + 1));
        if (i == NN - 1) offsets[NN] = excl + c;
    }
}
__global__ __launch_bounds__(256) void k_fill(const int* __restrict__ src,
                                              const int* __restrict__ dst,
                                              const int* __restrict__ rank,
                                              const int* __restrict__ offsets,
                                              int* __restrict__ edges) {
    int e = blockIdx.x * 256 + threadIdx.x;
    if (e < NE) {
        int s = src[e], d = dst[e], r = rank[e];
        edges[offsets[d] + r] = s;
    }
}

// ================= GEMM layer 1: G1[N,128] = dis[row]*(feat @ W1), fp32 in =========
// Two-pass B (17.4 KB halves) -> 34.8 KB LDS -> 4 blocks/CU.
__global__ __launch_bounds__(256, 4) void k_gemm1(const float* __restrict__ Xf,
                                                  const ushort* __restrict__ WT,
                                                  const float* __restrict__ dis,
                                                  ushort* __restrict__ Yb) {
    __shared__ ushort AL[64 * 136];
    __shared__ ushort BL[64 * 136];
    const int t = threadIdx.x;
    const int rbase = blockIdx.x * 64;
    if (blockIdx.x == 0 && t < 16) {   // zero row NN (gather target for pad lanes)
        uint4 z = make_uint4(0, 0, 0, 0);
        ((uint4*)(Yb + (size_t)NN * 128))[t] = z;
    }
    #pragma unroll
    for (int i = 0; i < 4; ++i) {
        int ch = t + 256 * i;
        int n = ch >> 4, c = ch & 15;
        *(int4*)(BL + n * 136 + c * 8) = *(const int4*)(WT + n * 128 + c * 8);
    }
    #pragma unroll
    for (int i = 0; i < 4; ++i) {
        int ch = t + 256 * i;
        int m = ch >> 4, c = ch & 15;
        int row = min(rbase + m, NN - 1);
        float4 f0 = *(const float4*)(Xf + (size_t)row * 128 + c * 8);
        float4 f1 = *(const float4*)(Xf + (size_t)row * 128 + c * 8 + 4);
        uint4 o;
        o.x = f2b2(f0.x, f0.y);
        o.y = f2b2(f0.z, f0.w);
        o.z = f2b2(f1.x, f1.y);
        o.w = f2b2(f1.z, f1.w);
        *(uint4*)(AL + m * 136 + c * 8) = o;
    }
    __syncthreads();
    const int wv = t >> 6, l = t & 63;
    const int m16 = l & 15, q = l >> 4;
    f32x4 acc[8];
    #pragma unroll
    for (int j = 0; j < 8; ++j) acc[j] = (f32x4){0.f, 0.f, 0.f, 0.f};
    #pragma unroll
    for (int kt = 0; kt < 4; ++kt) {
        bf16x8 a = *(const bf16x8*)(AL + (wv * 16 + m16) * 136 + kt * 32 + q * 8);
        #pragma unroll
        for (int j = 0; j < 4; ++j) {
            bf16x8 b = *(const bf16x8*)(BL + (j * 16 + m16) * 136 + kt * 32 + q * 8);
            acc[j] = __builtin_amdgcn_mfma_f32_16x16x32_bf16(a, b, acc[j], 0, 0, 0);
        }
    }
    __syncthreads();
    #pragma unroll
    for (int i = 0; i < 4; ++i) {
        int ch = t + 256 * i;
        int n = ch >> 4, c = ch & 15;
        *(int4*)(BL + n * 136 + c * 8) = *(const int4*)(WT + (64 + n) * 128 + c * 8);
    }
    __syncthreads();
    #pragma unroll
    for (int kt = 0; kt < 4; ++kt) {
        bf16x8 a = *(const bf16x8*)(AL + (wv * 16 + m16) * 136 + kt * 32 + q * 8);
        #pragma unroll
        for (int j = 0; j < 4; ++j) {
            bf16x8 b = *(const bf16x8*)(BL + (j * 16 + m16) * 136 + kt * 32 + q * 8);
            acc[4 + j] = __builtin_amdgcn_mfma_f32_16x16x32_bf16(a, b, acc[4 + j], 0, 0, 0);
        }
    }
    #pragma unroll
    for (int r = 0; r < 4; ++r) {
        int row = rbase + wv * 16 + q * 4 + r;
        if (row < NN) {
            float ds = dis[row];
            #pragma unroll
            for (int j = 0; j < 8; ++j)
                Yb[(size_t)row * 128 + j * 16 + m16] = f2b(acc[j][r] * ds);
        }
    }
}

// ======= FUSED: aggregate(G_prev) + bias + relu -> LDS -> GEMM(W,128) -> G_next =======
// Two-pass B (17.4 KB halves) -> LDS 34.8 KB -> 4 blocks/CU (validated optimum).
__global__ __launch_bounds__(256, 4) void k_fused128(const int* __restrict__ offsets,
                                                     const int* __restrict__ edges,
                                                     const float* __restrict__ dis,
                                                     const ushort* __restrict__ xw,
                                                     const float* __restrict__ bias,
                                                     const ushort* __restrict__ WT,
                                                     ushort* __restrict__ out) {
    __shared__ ushort AL[64 * 136];
    __shared__ ushort BL[64 * 136];
    const int t = threadIdx.x;
    const int rbase = blockIdx.x * 64;
    if (blockIdx.x == 0 && t < 16) {   // zero row NN of the OUTPUT buffer
        uint4 z = make_uint4(0, 0, 0, 0);
        ((uint4*)(out + (size_t)NN * 128))[t] = z;
    }
    // stage B half 0 (overlaps agg latency)
    #pragma unroll
    for (int i = 0; i < 4; ++i) {
        int ch = t + 256 * i;
        int n = ch >> 4, c = ch & 15;
        *(int4*)(BL + n * 136 + c * 8) = *(const int4*)(WT + n * 128 + c * 8);
    }
    const int wv = t >> 6, lane = t & 63;
    const int hl = lane & 15;
    const int qsel = lane & 48;
    const int qid = wv * 4 + (lane >> 4);   // 0..15
    #pragma unroll
    for (int iter = 0; iter < 4; ++iter) {
        const int m = qid * 4 + iter;
        const int n = rbase + m;
        const int nc = min(n, NN - 1);
        const int beg = offsets[nc], end = offsets[nc + 1];
        const int deg = end - beg;
        int s_l = (hl < deg) ? edges[beg + hl] : NN;   // NN = zero row
        uint4 v0 = ((const uint4*)(xw + (size_t)nc * 128))[hl];
        float a0 = b2f(v0.x & 0xffffu), a1 = b2f(v0.x >> 16);
        float a2 = b2f(v0.y & 0xffffu), a3 = b2f(v0.y >> 16);
        float a4 = b2f(v0.z & 0xffffu), a5 = b2f(v0.z >> 16);
        float a6 = b2f(v0.w & 0xffffu), a7 = b2f(v0.w >> 16);
        int degc = min(deg, 16);
        int qceil = (degc + 7) & ~7;                  // own quarter's ceiling
        int m1 = max(degc, __shfl_xor(degc, 16, 64));
        int dmax = max(m1, __shfl_xor(m1, 32, 64));
        int jceil = (dmax + 7) & ~7;
        for (int j = 0; j < jceil; j += 8) {
            if (j < qceil) {                          // quarter-uniform guard
                int s[8]; uint4 u[8];
                #pragma unroll
                for (int k = 0; k < 8; ++k) s[k] = __shfl(s_l, qsel + j + k, 64);
                #pragma unroll
                for (int k = 0; k < 8; ++k)
                    u[k] = ((const uint4*)(xw + (size_t)s[k] * 128))[hl];
                #pragma unroll
                for (int k = 0; k < 8; ++k) {
                    a0 += b2f(u[k].x & 0xffffu); a1 += b2f(u[k].x >> 16);
                    a2 += b2f(u[k].y & 0xffffu); a3 += b2f(u[k].y >> 16);
                    a4 += b2f(u[k].z & 0xffffu); a5 += b2f(u[k].z >> 16);
                    a6 += b2f(u[k].w & 0xffffu); a7 += b2f(u[k].w >> 16);
                }
            }
        }
        for (int jj = beg + 16; jj < end; ++jj) {   // deg>16 tail (rare)
            int s2 = edges[jj];
            uint4 u = ((const uint4*)(xw + (size_t)s2 * 128))[hl];
            a0 += b2f(u.x & 0xffffu); a1 += b2f(u.x >> 16);
            a2 += b2f(u.y & 0xffffu); a3 += b2f(u.y >> 16);
            a4 += b2f(u.z & 0xffffu); a5 += b2f(u.z >> 16);
            a6 += b2f(u.w & 0xffffu); a7 += b2f(u.w >> 16);
        }
        float d = dis[nc];
        float4 bv0 = ((const float4*)bias)[2 * hl];
        float4 bv1 = ((const float4*)bias)[2 * hl + 1];
        a0 = fmaxf(fmaf(a0, d, bv0.x), 0.f); a1 = fmaxf(fmaf(a1, d, bv0.y), 0.f);
        a2 = fmaxf(fmaf(a2, d, bv0.z), 0.f); a3 = fmaxf(fmaf(a3, d, bv0.w), 0.f);
        a4 = fmaxf(fmaf(a4, d, bv1.x), 0.f); a5 = fmaxf(fmaf(a5, d, bv1.y), 0.f);
        a6 = fmaxf(fmaf(a6, d, bv1.z), 0.f); a7 = fmaxf(fmaf(a7, d, bv1.w), 0.f);
        uint4 o;
        o.x = f2b2(a0, a1);
        o.y = f2b2(a2, a3);
        o.z = f2b2(a4, a5);
        o.w = f2b2(a6, a7);
        *(uint4*)(AL + m * 136 + hl * 8) = o;
    }
    __syncthreads();
    const int m16 = lane & 15, q = lane >> 4;
    f32x4 acc[8];
    #pragma unroll
    for (int j = 0; j < 8; ++j) acc[j] = (f32x4){0.f, 0.f, 0.f, 0.f};
    // GEMM pass 0: n-tiles 0..3 from BL (cols 0..63)
    #pragma unroll
    for (int kt = 0; kt < 4; ++kt) {
        bf16x8 a = *(const bf16x8*)(AL + (wv * 16 + m16) * 136 + kt * 32 + q * 8);
        #pragma unroll
        for (int j = 0; j < 4; ++j) {
            bf16x8 b = *(const bf16x8*)(BL + (j * 16 + m16) * 136 + kt * 32 + q * 8);
            acc[j] = __builtin_amdgcn_mfma_f32_16x16x32_bf16(a, b, acc[j], 0, 0, 0);
        }
    }
    __syncthreads();   // all reads of half 0 done before restage
    // stage B half 1 (n-rows 64..127)
    #pragma unroll
    for (int i = 0; i < 4; ++i) {
        int ch = t + 256 * i;
        int n = ch >> 4, c = ch & 15;
        *(int4*)(BL + n * 136 + c * 8) = *(const int4*)(WT + (64 + n) * 128 + c * 8);
    }
    __syncthreads();
    // GEMM pass 1: n-tiles 4..7 (cols 64..127)
    #pragma unroll
    for (int kt = 0; kt < 4; ++kt) {
        bf16x8 a = *(const bf16x8*)(AL + (wv * 16 + m16) * 136 + kt * 32 + q * 8);
        #pragma unroll
        for (int j = 0; j < 4; ++j) {
            bf16x8 b = *(const bf16x8*)(BL + (j * 16 + m16) * 136 + kt * 32 + q * 8);
            acc[4 + j] = __builtin_amdgcn_mfma_f32_16x16x32_bf16(a, b, acc[4 + j], 0, 0, 0);
        }
    }
    #pragma unroll
    for (int r = 0; r < 4; ++r) {
        int row = rbase + wv * 16 + q * 4 + r;
        if (row < NN) {
            float ds = dis[row];
            #pragma unroll
            for (int j = 0; j < 8; ++j)
                out[(size_t)row * 128 + j * 16 + m16] = f2b(acc[j][r] * ds);
        }
    }
}

// ======= FUSED: aggregate(G2) + bias + relu -> LDS -> GEMM(W3,48) -> Y40b =======
__global__ __launch_bounds__(256, 5) void k_fused40(const int* __restrict__ offsets,
                                                    const int* __restrict__ edges,
                                                    const float* __restrict__ dis,
                                                    const ushort* __restrict__ xw,
                                                    const float* __restrict__ bias,
                                                    const ushort* __restrict__ W3T,
                                                    ushort* __restrict__ out) {
    __shared__ ushort AL[64 * 136];
    __shared__ ushort BL[48 * 136];
    const int t = threadIdx.x;
    const int rbase = blockIdx.x * 64;
    if (blockIdx.x == 0 && t < 8) {   // zero row NN of Y40b (stride 64)
        uint4 z = make_uint4(0, 0, 0, 0);
        ((uint4*)(out + (size_t)NN * 64))[t] = z;
    }
    #pragma unroll
    for (int i = 0; i < 3; ++i) {
        int ch = t + 256 * i;
        int n = ch >> 4, c = ch & 15;
        *(int4*)(BL + n * 136 + c * 8) = *(const int4*)(W3T + n * 128 + c * 8);
    }
    const int wv = t >> 6, lane = t & 63;
    const int hl = lane & 15;
    const int qsel = lane & 48;
    const int qid = wv * 4 + (lane >> 4);
    #pragma unroll
    for (int iter = 0; iter < 4; ++iter) {
        const int m = qid * 4 + iter;
        const int n = rbase + m;
        const int nc = min(n, NN - 1);
        const int beg = offsets[nc], end = offsets[nc + 1];
        const int deg = end - beg;
        int s_l = (hl < deg) ? edges[beg + hl] : NN;
        uint4 v0 = ((const uint4*)(xw + (size_t)nc * 128))[hl];
        float a0 = b2f(v0.x & 0xffffu), a1 = b2f(v0.x >> 16);
        float a2 = b2f(v0.y & 0xffffu), a3 = b2f(v0.y >> 16);
        float a4 = b2f(v0.z & 0xffffu), a5 = b2f(v0.z >> 16);
        float a6 = b2f(v0.w & 0xffffu), a7 = b2f(v0.w >> 16);
        int degc = min(deg, 16);
        int qceil = (degc + 7) & ~7;
        int m1 = max(degc, __shfl_xor(degc, 16, 64));
        int dmax = max(m1, __shfl_xor(m1, 32, 64));
        int jceil = (dmax + 7) & ~7;
        for (int j = 0; j < jceil; j += 8) {
            if (j < qceil) {
                int s[8]; uint4 u[8];
                #pragma unroll
                for (int k = 0; k < 8; ++k) s[k] = __shfl(s_l, qsel + j + k, 64);
                #pragma unroll
                for (int k = 0; k < 8; ++k)
                    u[k] = ((const uint4*)(xw + (size_t)s[k] * 128))[hl];
                #pragma unroll
                for (int k = 0; k < 8; ++k) {
                    a0 += b2f(u[k].x & 0xffffu); a1 += b2f(u[k].x >> 16);
                    a2 += b2f(u[k].y & 0xffffu); a3 += b2f(u[k].y >> 16);
                    a4 += b2f(u[k].z & 0xffffu); a5 += b2f(u[k].z >> 16);
                    a6 += b2f(u[k].w & 0xffffu); a7 += b2f(u[k].w >> 16);
                }
            }
        }
        for (int jj = beg + 16; jj < end; ++jj) {
            int s2 = edges[jj];
            uint4 u = ((const uint4*)(xw + (size_t)s2 * 128))[hl];
            a0 += b2f(u.x & 0xffffu); a1 += b2f(u.x >> 16);
            a2 += b2f(u.y & 0xffffu); a3 += b2f(u.y >> 16);
            a4 += b2f(u.z & 0xffffu); a5 += b2f(u.z >> 16);
            a6 += b2f(u.w & 0xffffu); a7 += b2f(u.w >> 16);
        }
        float d = dis[nc];
        float4 bv0 = ((const float4*)bias)[2 * hl];
        float4 bv1 = ((const float4*)bias)[2 * hl + 1];
        a0 = fmaxf(fmaf(a0, d, bv0.x), 0.f); a1 = fmaxf(fmaf(a1, d, bv0.y), 0.f);
        a2 = fmaxf(fmaf(a2, d, bv0.z), 0.f); a3 = fmaxf(fmaf(a3, d, bv0.w), 0.f);
        a4 = fmaxf(fmaf(a4, d, bv1.x), 0.f); a5 = fmaxf(fmaf(a5, d, bv1.y), 0.f);
        a6 = fmaxf(fmaf(a6, d, bv1.z), 0.f); a7 = fmaxf(fmaf(a7, d, bv1.w), 0.f);
        uint4 o;
        o.x = f2b2(a0, a1);
        o.y = f2b2(a2, a3);
        o.z = f2b2(a4, a5);
        o.w = f2b2(a6, a7);
        *(uint4*)(AL + m * 136 + hl * 8) = o;
    }
    __syncthreads();
    const int m16 = lane & 15, q = lane >> 4;
    f32x4 acc[3];
    #pragma unroll
    for (int j = 0; j < 3; ++j) acc[j] = (f32x4){0.f, 0.f, 0.f, 0.f};
    #pragma unroll
    for (int kt = 0; kt < 4; ++kt) {
        bf16x8 a = *(const bf16x8*)(AL + (wv * 16 + m16) * 136 + kt * 32 + q * 8);
        #pragma unroll
        for (int j = 0; j < 3; ++j) {
            bf16x8 b = *(const bf16x8*)(BL + (j * 16 + m16) * 136 + kt * 32 + q * 8);
            acc[j] = __builtin_amdgcn_mfma_f32_16x16x32_bf16(a, b, acc[j], 0, 0, 0);
        }
    }
    #pragma unroll
    for (int r = 0; r < 4; ++r) {
        int row = rbase + wv * 16 + q * 4 + r;
        if (row < NN) {
            float ds = dis[row];
            #pragma unroll
            for (int j = 0; j < 3; ++j)
                out[(size_t)row * 64 + j * 16 + m16] = f2b(acc[j][r] * ds);
        }
    }
}

// ===== fused aggregate + bias + relu + log_softmax, F=40: FOUR nodes/wave =====
__global__ __launch_bounds__(256) void k_agg40_lsm(const int* __restrict__ offsets,
                                                   const int* __restrict__ edges,
                                                   const float* __restrict__ dis,
                                                   const ushort* __restrict__ xw,
                                                   const float* __restrict__ bias,
                                                   float* __restrict__ out) {
    const int t = threadIdx.x;
    const int wv = t >> 6, lane = t & 63;
    const int hl = lane & 15;
    const int qsel = lane & 48;
    const int n = (blockIdx.x * 4 + wv) * 4 + (lane >> 4);
    const bool nvalid = n < NN;
    const int nc = nvalid ? n : NN - 1;
    const bool act = hl < 10;   // lanes 0..9 hold feats 4*hl..4*hl+3 (40 total)
    const int beg = offsets[nc], end = offsets[nc + 1];
    const int deg = end - beg;
    int s_l = (hl < deg) ? edges[beg + hl] : NN;
    uint2 v0 = ((const uint2*)(xw + (size_t)nc * 64))[hl];
    float x0 = b2f(v0.x & 0xffffu), x1 = b2f(v0.x >> 16);
    float x2 = b2f(v0.y & 0xffffu), x3 = b2f(v0.y >> 16);
    int degc = min(deg, 16);
    int qceil = (degc + 7) & ~7;
    int m1 = max(degc, __shfl_xor(degc, 16, 64));
    int dmax = max(m1, __shfl_xor(m1, 32, 64));
    int jceil = (dmax + 7) & ~7;
    for (int j = 0; j < jceil; j += 8) {
        if (j < qceil) {
            int s[8]; uint2 u[8];
            #pragma unroll
            for (int k = 0; k < 8; ++k) s[k] = __shfl(s_l, qsel + j + k, 64);
            #pragma unroll
            for (int k = 0; k < 8; ++k)
                u[k] = ((const uint2*)(xw + (size_t)s[k] * 64))[hl];
            #pragma unroll
            for (int k = 0; k < 8; ++k) {
                x0 += b2f(u[k].x & 0xffffu); x1 += b2f(u[k].x >> 16);
                x2 += b2f(u[k].y & 0xffffu); x3 += b2f(u[k].y >> 16);
            }
        }
    }
    for (int jj = beg + 16; jj < end; ++jj) {
        int s2 = edges[jj];
        uint2 u = ((const uint2*)(xw + (size_t)s2 * 64))[hl];
        x0 += b2f(u.x & 0xffffu); x1 += b2f(u.x >> 16);
        x2 += b2f(u.y & 0xffffu); x3 += b2f(u.y >> 16);
    }
    float d = dis[nc];
    if (act) {
        float4 bv = ((const float4*)bias)[hl];
        x0 = fmaxf(fmaf(x0, d, bv.x), 0.f);
        x1 = fmaxf(fmaf(x1, d, bv.y), 0.f);
        x2 = fmaxf(fmaf(x2, d, bv.z), 0.f);
        x3 = fmaxf(fmaf(x3, d, bv.w), 0.f);
    }
    float m = act ? fmaxf(fmaxf(x0, x1), fmaxf(x2, x3)) : -1e30f;
    #pragma unroll
    for (int o = 8; o; o >>= 1) m = fmaxf(m, __shfl_xor(m, o, 64));
    float e = act ? (expf(x0 - m) + expf(x1 - m) + expf(x2 - m) + expf(x3 - m)) : 0.f;
    #pragma unroll
    for (int o = 8; o; o >>= 1) e += __shfl_xor(e, o, 64);
    if (act && nvalid) {
        float lg = m + logf(e);
        float4 o4 = make_float4(x0 - lg, x1 - lg, x2 - lg, x3 - lg);
        *(float4*)(out + (size_t)n * 40 + 4 * hl) = o4;
    }
}

// ================= launch =================
extern "C" void kernel_launch(void* const* d_in, const int* in_sizes, int n_in,
                              void* d_out, int out_size, void* d_ws, size_t ws_size,
                              hipStream_t stream) {
    const float* feat = (const float*)d_in[0];
    const int* ei = (const int*)d_in[1];
    const float* W1 = (const float*)d_in[2];
    const float* b1 = (const float*)d_in[3];
    const float* W2 = (const float*)d_in[4];
    const float* b2 = (const float*)d_in[5];
    const float* W3 = (const float*)d_in[6];
    const float* b3 = (const float*)d_in[7];
    const int* src = ei;
    const int* dst = ei + NE;
    float* out = (float*)d_out;

    char* w = (char*)d_ws;
    int* cnt = (int*)w;        w += 100352 * 4;
    float* dis = (float*)w;    w += 100352 * 4;
    int* offsets = (int*)w;    w += 100608 * 4;
    int* rank = (int*)w;       w += 600064 * 4;
    int* blocksum = (int*)w;   w += 512 * 4;
    int* edges = (int*)w;      w += 600064 * 4;
    ushort* WTall = (ushort*)w; w += 39168 * 2;
    ushort* W1T = WTall;
    ushort* W2T = WTall + 16384;
    ushort* W3T = WTall + 32768;
    ushort* bufYb = (ushort*)w; w += (size_t)NPAD * 128 * 2;
    ushort* bufXb = (ushort*)w; w += (size_t)NPAD * 128 * 2;
    ushort* Y40b = (ushort*)w;  w += (size_t)NPAD * 64 * 2;

    const int B = 256;
    #define CDIV(a, b) (((a) + (b) - 1) / (b))

    // CSR build (reused by all layers); weight cast rides the first launch
    k_init_castW<<<NBLK + CDIV(38912, B), B, 0, stream>>>(cnt, W1, W2, W3, WTall);
    k_cnt<<<CDIV(NE, B), B, 0, stream>>>(dst, cnt, rank);
    k_blockred<<<NBLK, B, 0, stream>>>(cnt, blocksum);
    k_offsets<<<NBLK, B, 0, stream>>>(cnt, blocksum, offsets, dis);
    k_fill<<<CDIV(NE, B), B, 0, stream>>>(src, dst, rank, offsets, edges);

    // layer 1 GEMM (fp32 input, fused cast; epilogue scales by dis)
    k_gemm1<<<CDIV(NN, 64), B, 0, stream>>>(feat, W1T, dis, bufYb);
    // fused agg1 + gemm2 (two-pass B, 4 blocks/CU — validated optimum)
    k_fused128<<<CDIV(NN, 64), B, 0, stream>>>(offsets, edges, dis, bufYb, b1, W2T, bufXb);
    // fused agg2 + gemm40
    k_fused40<<<CDIV(NN, 64), B, 0, stream>>>(offsets, edges, dis, bufXb, b2, W3T, Y40b);
    // final aggregate + log_softmax (4 nodes/wave)
    k_agg40_lsm<<<CDIV(NN, 16), B, 0, stream>>>(offsets, edges, dis, Y40b, b3, out);
    #undef CDIV
}